// Round 4
// baseline (1809.652 us; speedup 1.0000x reference)
//
#include <hip/hip_runtime.h>
#include <hip/hip_bf16.h>

// Problem constants (fixed by setup_inputs)
#define H    300
#define KP   320            // K padded to multiple of 32
#define BM   2048           // num molecules
#define SEG  48
#define NTOK (BM*SEG)       // 98304
#define G    900            // 3*H
#define GW   1024           // padded weight rows (gi order): 19ct*48 = 912, pad to 1024
#define XPW  912            // xp row stride (gi cols; 912 = 19*48)
#define MOLW 16             // molecules per recurrent workgroup
#define NCH  10             // K-chunks of 32 (KP/32)
#define BKX  64             // xp_gemm K-step

typedef __attribute__((ext_vector_type(8))) short short8;
typedef __attribute__((ext_vector_type(4))) float f32x4;

__device__ __forceinline__ float us2f(unsigned short u) { return __uint_as_float(((unsigned)u) << 16); }
__device__ __forceinline__ unsigned short bfb(float f) {
    __hip_bfloat16 b = __float2bfloat16(f);
    return *(unsigned short*)&b;
}
__device__ __forceinline__ void gload16(const void* g, void* l) {
    __builtin_amdgcn_global_load_lds((const __attribute__((address_space(1))) unsigned*)g,
                                     (__attribute__((address_space(3))) unsigned*)l, 16, 0, 0);
}

// gate-interleaved row map: R = ct*48 + g*16 + i  <->  original gate-row g*300 + ct*16 + i
// ---------------- prep: weights -> gi-ordered padded bf16, biases -> gi-ordered f32 ----------------
__global__ void prep_weights(const float* wih_f, const float* whh_f, const float* bih_f,
                             const float* wih_b, const float* whh_b, const float* bih_b,
                             __hip_bfloat16* wih, __hip_bfloat16* whh, float* bih) {
    int idx = blockIdx.x * 256 + threadIdx.x;
    const int wn = 2 * GW * KP;
    if (idx < wn) {                          // w_ih (gi rows)
        int d = idx / (GW * KP);
        int R = (idx / KP) % GW;
        int k = idx % KP;
        int ct = R / 48, rem = R % 48, g = rem / 16, i = rem % 16;
        int col = ct * 16 + i;
        const float* src = d ? wih_b : wih_f;
        float v = (R < 912 && col < H && k < H) ? src[(g * H + col) * H + k] : 0.f;
        wih[idx] = __float2bfloat16(v);
        return;
    }
    idx -= wn;
    if (idx < wn) {                          // w_hh (gi rows, same geometry)
        int d = idx / (GW * KP);
        int R = (idx / KP) % GW;
        int k = idx % KP;
        int ct = R / 48, rem = R % 48, g = rem / 16, i = rem % 16;
        int col = ct * 16 + i;
        const float* src = d ? whh_b : whh_f;
        float v = (R < 912 && col < H && k < H) ? src[(g * H + col) * H + k] : 0.f;
        whh[idx] = __float2bfloat16(v);
        return;
    }
    idx -= wn;
    if (idx < 2 * GW) {                      // b_ih (gi rows)
        int d = idx / GW;
        int R = idx % GW;
        int ct = R / 48, rem = R % 48, g = rem / 16, i = rem % 16;
        int col = ct * 16 + i;
        const float* src = d ? bih_b : bih_f;
        bih[idx] = (R < 912 && col < H) ? src[g * H + col] : 0.f;
    }
}

// ---------------- prep: message = bf16(relu(x + bias)), K-padded ----------------
__global__ void prep_msg(const float* x, const float* bias, __hip_bfloat16* msg) {
    int idx = blockIdx.x * 256 + threadIdx.x;      // over NTOK*KP
    if (idx >= NTOK * KP) return;
    int i = idx / KP, k = idx % KP;
    float v = 0.f;
    if (k < H) {
        v = x[i * H + k] + bias[k];
        v = v > 0.f ? v : 0.f;
    }
    msg[idx] = __float2bfloat16(v);
}

// ---------------- prep: h0 = segment_max(x) ----------------
__global__ void h0_kernel(const float* x, float* h0) {
    int m = blockIdx.x;
    for (int c = threadIdx.x; c < H; c += blockDim.x) {
        const float* base = x + (long long)m * SEG * H + c;
        float v = -INFINITY;
        for (int t = 0; t < SEG; t++) v = fmaxf(v, base[t * H]);
        h0[m * H + c] = v;
    }
}

// ---------------- xp = msg @ w_ih^T + b_ih  (m97-style; output cols in gi order) ----------------
__global__ __launch_bounds__(256) void xp_gemm(const __hip_bfloat16* msg, const __hip_bfloat16* wih,
                                               const float* bih, __hip_bfloat16* xp) {
    int d = blockIdx.z;
    const __hip_bfloat16* A  = msg;
    const __hip_bfloat16* Bw = wih + d * GW * KP;
    const float* bi = bih + d * GW;
    __hip_bfloat16* out = xp + (long long)d * NTOK * XPW;

    __shared__ __hip_bfloat16 sA[128 * BKX];   // 16 KB
    __shared__ __hip_bfloat16 sB[128 * BKX];   // 16 KB
    const short* sAs = (const short*)sA;
    const short* sBs = (const short*)sB;

    int tid = threadIdx.x;
    int lane = tid & 63, wid = tid >> 6;
    int l15 = lane & 15, quad = lane >> 4;
    int mblk = blockIdx.x * 128, nblk = blockIdx.y * 128;
    int mbase = (wid >> 1) * 64, nbase = (wid & 1) * 64;

    int srow = wid * 32 + (lane >> 3);          // local row at j=0 (rows += 8 per j)
    int scc  = (lane & 7) ^ (srow & 7);         // swizzled source chunk-in-row
    const short* gA0 = (const short*)A  + (long long)(mblk + srow) * KP + scc * 8;
    const short* gB0 = (const short*)Bw + (long long)(nblk + srow) * KP + scc * 8;
    int xsw = (l15 & 7) << 3;                   // read-side XOR (shorts)

    f32x4 acc[4][4] = {};
    for (int kc = 0; kc < KP / BKX; kc++) {
#pragma unroll
        for (int j = 0; j < 4; j++)
            gload16(gA0 + (long long)j * 8 * KP + kc * BKX, (char*)sA + (wid * 4 + j) * 1024);
#pragma unroll
        for (int j = 0; j < 4; j++)
            gload16(gB0 + (long long)j * 8 * KP + kc * BKX, (char*)sB + (wid * 4 + j) * 1024);
        __syncthreads();

        short8 af[4][2], bf[4][2];
#pragma unroll
        for (int i = 0; i < 4; i++)
#pragma unroll
            for (int kh = 0; kh < 2; kh++)
                af[i][kh] = *(const short8*)(sAs + (mbase + i * 16 + l15) * BKX + ((kh * 32 + quad * 8) ^ xsw));
#pragma unroll
        for (int j = 0; j < 4; j++)
#pragma unroll
            for (int kh = 0; kh < 2; kh++)
                bf[j][kh] = *(const short8*)(sBs + (nbase + j * 16 + l15) * BKX + ((kh * 32 + quad * 8) ^ xsw));
#pragma unroll
        for (int i = 0; i < 4; i++)
#pragma unroll
            for (int j = 0; j < 4; j++) {
                acc[i][j] = __builtin_amdgcn_mfma_f32_16x16x32_bf16(af[i][0], bf[j][0], acc[i][j], 0, 0, 0);
                acc[i][j] = __builtin_amdgcn_mfma_f32_16x16x32_bf16(af[i][1], bf[j][1], acc[i][j], 0, 0, 0);
            }
        __syncthreads();
    }

#pragma unroll
    for (int i = 0; i < 4; i++)
#pragma unroll
        for (int j = 0; j < 4; j++) {
            int col = nblk + nbase + j * 16 + l15;
            if (col < XPW) {
                float bv = bi[col];
#pragma unroll
                for (int r = 0; r < 4; r++) {
                    int row = mblk + mbase + i * 16 + quad * 4 + r;
                    out[(long long)row * XPW + col] = __float2bfloat16(acc[i][j][r] + bv);
                }
            }
        }
}

// ---------------- persistent bidirectional GRU, LDS-staged weights ----------------
// grid (128, 2) = 256 WGs x 1024 thr = 16 waves, 1 WG/CU.
// w_hh streamed per step as 10 x 64KB K-chunks via global_load_lds (dest-reg-free DMA,
// 64 in flight per WG) into double-buffered LDS; each wave owns whole ct column-tiles
// (all 3 gates) so the GRU pointwise runs in-register on the MFMA accumulators.
__global__ __launch_bounds__(1024) void gru_kernel(const __hip_bfloat16* whh_all, const float* bhh_f,
                                                   const float* bhh_b, const __hip_bfloat16* xp,
                                                   const float* h0, float* out) {
    int grp = blockIdx.x;      // molecule group, 0..127
    int d   = blockIdx.y;      // direction
    const char* whhd = (const char*)(whh_all + (long long)d * GW * KP);
    const float* bhh = d ? bhh_b : bhh_f;
    const __hip_bfloat16* xpd = xp + (long long)d * NTOK * XPW;

    int tid = threadIdx.x;
    int lane = tid & 63, wid = tid >> 6;           // wid 0..15
    int l15 = lane & 15, quad = lane >> 4;
    int xor3 = (l15 & 3) ^ ((l15 >> 2) & 3);       // b-frag bank swizzle (2-way = free)

    __shared__ __hip_bfloat16 hB[MOLW * 328];      // 10,496 B  bf16 h (A-operand), stride 328
    __shared__ char bufA[65536];                   // chunk double-buffer (64 KB each)
    __shared__ char bufB[65536];

    int mol0 = grp * MOLW;

    // ---- DMA source bases (chunk 0): LDS linear dest, XOR-pre-swizzled source ----
    const char* dmasrc[4];
#pragma unroll
    for (int j = 0; j < 4; j++) {
        int R = (wid * 4 + j) * 16 + (lane >> 2);
        int s = lane & 3;
        int sw = s ^ (R & 3) ^ ((R >> 2) & 3);
        dmasrc[j] = whhd + R * (KP * 2) + sw * 16;
    }

    // ---- ct ownership: wave w owns ct=w; waves 0-2 also own ct 16-18 ----
    int nct = (wid < 3) ? 2 : 1;

    // ---- zero hB (incl. K-pad cols 300..327) ----
    for (int e = tid; e < MOLW * 328; e += 1024) hB[e] = __float2bfloat16(0.f);
    __syncthreads();

    // ---- per-ct state: bias, carried h (4 mols/lane), hB init ----
    float bvv[2][3];
    f32x4 hreg[2];
#pragma unroll
    for (int cc = 0; cc < 2; cc++) {
        if (cc < nct) {
            int ct = cc ? 16 + wid : wid;
            int col = ct * 16 + l15;
            bool cv = col < H;
#pragma unroll
            for (int g = 0; g < 3; g++)
                bvv[cc][g] = cv ? bhh[g * H + col] : 0.f;
#pragma unroll
            for (int r = 0; r < 4; r++) {
                float hv = cv ? h0[(size_t)(mol0 + quad * 4 + r) * H + col] : 0.f;
                hreg[cc][r] = hv;
                if (cv) hB[(quad * 4 + r) * 328 + col] = __float2bfloat16(hv);
            }
        }
    }

    // ---- prologue: stage chunk 0 -> bufA ----
#pragma unroll
    for (int j = 0; j < 4; j++)
        gload16(dmasrc[j], bufA + (wid * 4 + j) * 1024);
    __syncthreads();   // h-init visible + chunk0 staged

    for (int t = 0; t < SEG; t++) {
        int tt = d ? (SEG - 1 - t) : t;

        f32x4 acc[2][3] = {};
        unsigned short xv[2][3][4];

        auto phase = [&](int c, const char* curb, char* nxtb) {
            int nk = (c + 1) % NCH;
            // stage next chunk (for c==9: chunk0 of next step — w_hh is t-invariant)
#pragma unroll
            for (int j = 0; j < 4; j++)
                gload16(dmasrc[j] + nk * 64, nxtb + (wid * 4 + j) * 1024);
            if (c == 8) {
                // xp gate inputs for this step (drained by this phase's barrier)
#pragma unroll
                for (int cc = 0; cc < 2; cc++)
                    if (cc < nct) {
                        int ct = cc ? 16 + wid : wid;
#pragma unroll
                        for (int r = 0; r < 4; r++) {
                            long long tok = (long long)(mol0 + quad * 4 + r) * SEG + tt;
                            const unsigned short* xrow = (const unsigned short*)(xpd + tok * XPW + ct * 48 + l15);
#pragma unroll
                            for (int g = 0; g < 3; g++)
                                xv[cc][g][r] = xrow[g * 16];
                        }
                    }
            }
            // compute chunk c
            short8 aq = *(const short8*)((const char*)hB + l15 * 656 + c * 64 + quad * 16);
#pragma unroll
            for (int cc = 0; cc < 2; cc++)
                if (cc < nct) {
                    int ct = cc ? 16 + wid : wid;
#pragma unroll
                    for (int g = 0; g < 3; g++) {
                        short8 bq = *(const short8*)(curb + (ct * 48 + g * 16 + l15) * 64 + ((quad ^ xor3) << 4));
                        acc[cc][g] = __builtin_amdgcn_mfma_f32_16x16x32_bf16(aq, bq, acc[cc][g], 0, 0, 0);
                    }
                }
            __syncthreads();   // drains DMA(next) + all waves done reading curb
        };

#pragma unroll
        for (int c2 = 0; c2 < 5; c2++) {
            phase(2 * c2,     bufA, bufB);
            phase(2 * c2 + 1, bufB, bufA);
        }

        // ---- pointwise GRU gates: fully in-register on accumulators ----
#pragma unroll
        for (int cc = 0; cc < 2; cc++)
            if (cc < nct) {
                int ct = cc ? 16 + wid : wid;
                int col = ct * 16 + l15;
                bool cv = col < H;
#pragma unroll
                for (int r = 0; r < 4; r++) {
                    float hr = acc[cc][0][r] + bvv[cc][0];
                    float hz = acc[cc][1][r] + bvv[cc][1];
                    float hn = acc[cc][2][r] + bvv[cc][2];
                    float xr = us2f(xv[cc][0][r]);
                    float xz = us2f(xv[cc][1][r]);
                    float xn = us2f(xv[cc][2][r]);
                    float rg = 1.f / (1.f + __expf(-(xr + hr)));
                    float zg = 1.f / (1.f + __expf(-(xz + hz)));
                    float ni = xn + rg * hn;
                    float ng = 1.f - 2.f / (__expf(2.f * ni) + 1.f);
                    float hnew = (1.f - zg) * ng + zg * hreg[cc][r];
                    hreg[cc][r] = hnew;
                    if (cv) {
                        hB[(quad * 4 + r) * 328 + col] = __float2bfloat16(hnew);
                        long long tok = (long long)(mol0 + quad * 4 + r) * SEG + tt;
                        out[tok * 600 + d * 300 + col] = hnew;
                    }
                }
            }
        __syncthreads();   // hB updates visible before next step's A-fragments
    }
}

extern "C" void kernel_launch(void* const* d_in, const int* in_sizes, int n_in,
                              void* d_out, int out_size, void* d_ws, size_t ws_size,
                              hipStream_t stream) {
    const float* x     = (const float*)d_in[0];
    const float* bias  = (const float*)d_in[4];
    const float* wih_f = (const float*)d_in[5];
    const float* whh_f = (const float*)d_in[6];
    const float* bih_f = (const float*)d_in[7];
    const float* bhh_f = (const float*)d_in[8];
    const float* wih_b = (const float*)d_in[9];
    const float* whh_b = (const float*)d_in[10];
    const float* bih_b = (const float*)d_in[11];
    const float* bhh_b = (const float*)d_in[12];
    float* out = (float*)d_out;

    // Workspace layout (total 426,614,784 B ~= 406.9 MiB)
    char* ws = (char*)d_ws;
    __hip_bfloat16* msg = (__hip_bfloat16*)(ws);                    //  62,914,560 B
    __hip_bfloat16* wih = (__hip_bfloat16*)(ws + 62914560LL);       //   1,310,720 B
    __hip_bfloat16* whh = (__hip_bfloat16*)(ws + 64225280LL);       //   1,310,720 B (gi, 1024 rows/dir)
    float*          bih = (float*)         (ws + 65536000LL);       //       8,192 B
    float*          h0  = (float*)         (ws + 65544192LL);       //   2,457,600 B
    __hip_bfloat16* xp  = (__hip_bfloat16*)(ws + 68001792LL);       // 358,612,992 B

    hipLaunchKernelGGL(prep_weights, dim3((2*GW*KP + 2*GW*KP + 2*GW + 255) / 256), dim3(256), 0, stream,
                       wih_f, whh_f, bih_f, wih_b, whh_b, bih_b, wih, whh, bih);
    hipLaunchKernelGGL(prep_msg, dim3((NTOK * KP + 255) / 256), dim3(256), 0, stream, x, bias, msg);
    hipLaunchKernelGGL(h0_kernel, dim3(BM), dim3(256), 0, stream, x, h0);
    hipLaunchKernelGGL(xp_gemm, dim3(NTOK / 128, GW / 128, 2), dim3(256), 0, stream, msg, wih, bih, xp);
    hipLaunchKernelGGL(gru_kernel, dim3(BM / MOLW, 2), dim3(1024), 0, stream, whh, bhh_f, bhh_b, xp, h0, out);
}